// Round 1
// baseline (118.086 us; speedup 1.0000x reference)
//
#include <hip/hip_runtime.h>
#include <math.h>

// SE block: x[32,512,56,56] fp32
//   squeeze = mean over (H,W) -> [32,512]
//   h = relu(squeeze @ w1^T + b1)      w1: [32,512]
//   e = sigmoid(h @ w2^T + b2)         w2: [512,32]
//   out = x * e[b,c] broadcast

#define SE_C 512
#define SE_CR 32
#define SE_B 32
#define SPATIAL 3136            // 56*56
#define VEC_PER_ROW 784         // 3136/4 float4s per (b,c) row

// ---------------- Kernel 1: global average pool ----------------
// One block per (b,c) row. 256 threads, float4 loads, wave+LDS reduce.
__global__ __launch_bounds__(256) void se_squeeze(const float* __restrict__ x,
                                                  float* __restrict__ sq) {
    const int row = blockIdx.x;  // b*512 + c, in [0, 16384)
    const float4* p = reinterpret_cast<const float4*>(x) + (size_t)row * VEC_PER_ROW;
    float s = 0.f;
    for (int i = threadIdx.x; i < VEC_PER_ROW; i += 256) {
        float4 v = p[i];
        s += (v.x + v.y) + (v.z + v.w);
    }
    // reduce within wave (64 lanes)
    #pragma unroll
    for (int off = 32; off > 0; off >>= 1) s += __shfl_down(s, off, 64);
    __shared__ float wsum[4];
    const int wave = threadIdx.x >> 6;
    if ((threadIdx.x & 63) == 0) wsum[wave] = s;
    __syncthreads();
    if (threadIdx.x == 0) {
        float t = (wsum[0] + wsum[1]) + (wsum[2] + wsum[3]);
        sq[row] = t * (1.0f / (float)SPATIAL);
    }
}

// ---------------- Kernel 2: excitation (two tiny FCs) ----------------
// One block per batch. 512 threads.
__global__ __launch_bounds__(512) void se_excite(const float* __restrict__ sq,
                                                 const float* __restrict__ w1,
                                                 const float* __restrict__ b1,
                                                 const float* __restrict__ w2,
                                                 const float* __restrict__ b2,
                                                 float* __restrict__ e) {
    const int b = blockIdx.x;
    __shared__ float s_lds[SE_C];
    __shared__ float h_lds[SE_CR];
    const int t = threadIdx.x;
    s_lds[t] = sq[b * SE_C + t];
    __syncthreads();
    if (t < SE_CR) {
        float acc = b1[t];
        const float* wr = w1 + t * SE_C;   // w1[j, :]
        for (int c = 0; c < SE_C; ++c) acc += s_lds[c] * wr[c];
        h_lds[t] = fmaxf(acc, 0.f);
    }
    __syncthreads();
    {
        float acc = b2[t];
        const float* wr = w2 + t * SE_CR;  // w2[c, :]
        #pragma unroll
        for (int j = 0; j < SE_CR; ++j) acc += h_lds[j] * wr[j];
        e[b * SE_C + t] = 1.0f / (1.0f + expf(-acc));
    }
}

// ---------------- Kernel 3: broadcast scale ----------------
// Grid-stride over float4s; row = vec_idx / 784.
__global__ __launch_bounds__(256) void se_scale(const float* __restrict__ x,
                                                const float* __restrict__ e,
                                                float* __restrict__ out,
                                                int nvec) {
    const int stride = gridDim.x * 256;
    for (int i = blockIdx.x * 256 + threadIdx.x; i < nvec; i += stride) {
        float4 v = reinterpret_cast<const float4*>(x)[i];
        const float scale = e[i / VEC_PER_ROW];
        float4 o;
        o.x = v.x * scale;
        o.y = v.y * scale;
        o.z = v.z * scale;
        o.w = v.w * scale;
        reinterpret_cast<float4*>(out)[i] = o;
    }
}

extern "C" void kernel_launch(void* const* d_in, const int* in_sizes, int n_in,
                              void* d_out, int out_size, void* d_ws, size_t ws_size,
                              hipStream_t stream) {
    const float* x  = (const float*)d_in[0];
    const float* w1 = (const float*)d_in[1];
    const float* b1 = (const float*)d_in[2];
    const float* w2 = (const float*)d_in[3];
    const float* b2 = (const float*)d_in[4];
    float* out = (float*)d_out;

    float* sq = (float*)d_ws;                 // [32*512]
    float* e  = sq + SE_B * SE_C;             // [32*512]

    const int rows = SE_B * SE_C;             // 16384
    se_squeeze<<<rows, 256, 0, stream>>>(x, sq);
    se_excite<<<SE_B, 512, 0, stream>>>(sq, w1, b1, w2, b2, e);

    const int nvec = rows * VEC_PER_ROW;      // 12,845,056 float4s
    se_scale<<<8192, 256, 0, stream>>>(x, e, out, nvec);
}

// Round 2
// 105.991 us; speedup vs baseline: 1.1141x; 1.1141x over previous
//
#include <hip/hip_runtime.h>
#include <math.h>

// SE block: x[32,512,56,56] fp32
//   squeeze = mean over (H,W) -> [32,512]
//   h = relu(squeeze @ w1^T + b1)      w1: [32,512]
//   e = sigmoid(h @ w2^T + b2)         w2: [512,32]
//   out = x * e[b,c] broadcast
//
// Memory-bound: min traffic = read x (205 MB) + re-read x (L3-resident if out
// stores don't evict it) + write out (205 MB). Nontemporal stores keep x in L3.

#define SE_C 512
#define SE_CR 32
#define SE_B 32
#define SPATIAL 3136            // 56*56
#define VEC_PER_ROW 784         // 3136/4 float4s per (b,c) row

typedef float f4 __attribute__((ext_vector_type(4)));

// ---------------- Kernel 1: global average pool ----------------
// One block per (b,c) row. 256 threads, float4 loads, shuffle+LDS reduce.
// Regular (caching) loads: we WANT x resident in L3 for the scale kernel.
__global__ __launch_bounds__(256) void se_squeeze(const f4* __restrict__ x,
                                                  float* __restrict__ sq) {
    const int row = blockIdx.x;  // b*512 + c, in [0, 16384)
    const f4* p = x + (size_t)row * VEC_PER_ROW;
    float s = 0.f;
    for (int i = threadIdx.x; i < VEC_PER_ROW; i += 256) {
        f4 v = p[i];
        s += (v.x + v.y) + (v.z + v.w);
    }
    // reduce within wave (64 lanes)
    #pragma unroll
    for (int off = 32; off > 0; off >>= 1) s += __shfl_down(s, off, 64);
    __shared__ float wsum[4];
    const int wave = threadIdx.x >> 6;
    if ((threadIdx.x & 63) == 0) wsum[wave] = s;
    __syncthreads();
    if (threadIdx.x == 0) {
        float t = (wsum[0] + wsum[1]) + (wsum[2] + wsum[3]);
        sq[row] = t * (1.0f / (float)SPATIAL);
    }
}

// ---------------- Kernel 2: excitation (two tiny FCs) ----------------
// One block per batch. 512 threads. ~2 MFLOP total — noise.
__global__ __launch_bounds__(512) void se_excite(const float* __restrict__ sq,
                                                 const float* __restrict__ w1,
                                                 const float* __restrict__ b1,
                                                 const float* __restrict__ w2,
                                                 const float* __restrict__ b2,
                                                 float* __restrict__ e) {
    const int b = blockIdx.x;
    __shared__ float s_lds[SE_C];
    __shared__ float h_lds[SE_CR];
    const int t = threadIdx.x;
    s_lds[t] = sq[b * SE_C + t];
    __syncthreads();
    if (t < SE_CR) {
        float acc = b1[t];
        const float* wr = w1 + t * SE_C;   // w1[j, :]
        for (int c = 0; c < SE_C; ++c) acc += s_lds[c] * wr[c];
        h_lds[t] = fmaxf(acc, 0.f);
    }
    __syncthreads();
    {
        float acc = b2[t];
        const float* wr = w2 + t * SE_CR;  // w2[c, :]
        #pragma unroll
        for (int j = 0; j < SE_CR; ++j) acc += h_lds[j] * wr[j];
        e[b * SE_C + t] = 1.0f / (1.0f + expf(-acc));
    }
}

// ---------------- Kernel 3: broadcast scale ----------------
// One block per (b,c) row: scale is a single wave-uniform scalar (no div).
// Nontemporal stores: out is never re-read; don't evict x from L3.
__global__ __launch_bounds__(256) void se_scale(const f4* __restrict__ x,
                                                const float* __restrict__ e,
                                                f4* __restrict__ out) {
    const int row = blockIdx.x;
    const float s = e[row];
    const f4* px = x + (size_t)row * VEC_PER_ROW;
    f4* po = out + (size_t)row * VEC_PER_ROW;
    for (int i = threadIdx.x; i < VEC_PER_ROW; i += 256) {
        f4 v = px[i];
        f4 o = v * s;
        __builtin_nontemporal_store(o, po + i);
    }
}

extern "C" void kernel_launch(void* const* d_in, const int* in_sizes, int n_in,
                              void* d_out, int out_size, void* d_ws, size_t ws_size,
                              hipStream_t stream) {
    const float* x  = (const float*)d_in[0];
    const float* w1 = (const float*)d_in[1];
    const float* b1 = (const float*)d_in[2];
    const float* w2 = (const float*)d_in[3];
    const float* b2 = (const float*)d_in[4];
    float* out = (float*)d_out;

    float* sq = (float*)d_ws;                 // [32*512]
    float* e  = sq + SE_B * SE_C;             // [32*512]

    const int rows = SE_B * SE_C;             // 16384
    se_squeeze<<<rows, 256, 0, stream>>>((const f4*)x, sq);
    se_excite<<<SE_B, 512, 0, stream>>>(sq, w1, b1, w2, b2, e);
    se_scale<<<rows, 256, 0, stream>>>((const f4*)x, e, (f4*)out);
}